// Round 1
// baseline (678.674 us; speedup 1.0000x reference)
//
#include <hip/hip_runtime.h>

// ---------------------------------------------------------------------------
// SparseAttention on MI355X (gfx950)
// hidden=2048, heads=16, d=128, topk=256, N=2048, B=1
//
// Ranking path (fp32/fp64, exact):  imp[h,m] = hs[m,:] . U[:,h]
//   where U[i,h] = sum_{j in head h} Wk[i,j]*qbar[j],  qbar = mean_n(HS) @ Wq + bq
// Value path (bf16 MFMA, m97 structure): QKV GEMMs, gather, QK_sel, softmax, PV, O.
// ---------------------------------------------------------------------------

typedef __attribute__((ext_vector_type(8))) short bf16x8;
typedef __attribute__((ext_vector_type(4))) float f32x4;

__device__ __forceinline__ unsigned short f2bf(float x) {
    unsigned u = __float_as_uint(x);
    u += 0x7fffu + ((u >> 16) & 1u);      // round to nearest even
    return (unsigned short)(u >> 16);
}
__device__ __forceinline__ float bf2f(unsigned short h) {
    return __uint_as_float(((unsigned)h) << 16);
}

__device__ __forceinline__ void load_lds16(const unsigned short* g, unsigned short* l) {
    __builtin_amdgcn_global_load_lds(
        (const __attribute__((address_space(1))) unsigned int*)g,
        (__attribute__((address_space(3))) unsigned int*)l,
        16, 0, 0);
}

// ---------------------------------------------------------------------------
// Generic bf16 MFMA GEMM:  C[b,m,n] = alpha * sum_k A[b,m,k]*Bt[b,n,k] (+ bias[b,n])
// A, Bt bf16 (ushort bits); C fp32 or bf16. Tile 128x128, BK=32, 256 threads.
// All of M, N multiples of 128; K multiple of 32 (true for every call here).
// ---------------------------------------------------------------------------
template <bool OUT_BF16>
__global__ __launch_bounds__(256) void gemm_bf16(
    const unsigned short* __restrict__ A, long lda, long strideA,
    const unsigned short* __restrict__ Bt, long ldb, long strideB,
    void* __restrict__ Cv, long ldc, long strideC,
    const float* __restrict__ bias, long biasStride,
    int M, int N, int K, float alpha)
{
    __shared__ __align__(16) unsigned short As[128][32];   // 8 KB
    __shared__ __align__(16) unsigned short Bs[128][32];   // 8 KB (Bt rows: [n][k])

    const int tid  = threadIdx.x;
    const int lane = tid & 63;
    const int wave = tid >> 6;                 // 0..3
    const int wm = wave >> 1, wn = wave & 1;   // 2x2 wave grid, each wave 64x64

    const int bm = blockIdx.y * 128;
    const int bn = blockIdx.x * 128;
    const int b  = blockIdx.z;

    const unsigned short* Ab = A  + (long)b * strideA;
    const unsigned short* Bb = Bt + (long)b * strideB;

    f32x4 acc[4][4];
#pragma unroll
    for (int i = 0; i < 4; i++)
#pragma unroll
        for (int j = 0; j < 4; j++) acc[i][j] = f32x4{0.f, 0.f, 0.f, 0.f};

    const int rg = wave * 32;          // this wave stages rows [rg, rg+32) of each tile
    const int lr = lane >> 2;          // 0..15 : row within 16-row group
    const int lc = (lane & 3) * 8;     // 0,8,16,24 : bf16 col offset (16B chunk)

    for (int k0 = 0; k0 < K; k0 += 32) {
        __syncthreads();   // previous iteration's frag reads must finish
#pragma unroll
        for (int q = 0; q < 2; q++) {
            const unsigned short* g = Ab + (long)(bm + rg + q * 16 + lr) * lda + k0 + lc;
            load_lds16(g, &As[rg + q * 16][0]);
        }
#pragma unroll
        for (int q = 0; q < 2; q++) {
            const unsigned short* g = Bb + (long)(bn + rg + q * 16 + lr) * ldb + k0 + lc;
            load_lds16(g, &Bs[rg + q * 16][0]);
        }
        __syncthreads();

        bf16x8 af[4], bf[4];
#pragma unroll
        for (int s = 0; s < 4; s++)
            af[s] = *(const bf16x8*)&As[wm * 64 + s * 16 + (lane & 15)][(lane >> 4) * 8];
#pragma unroll
        for (int t = 0; t < 4; t++)
            bf[t] = *(const bf16x8*)&Bs[wn * 64 + t * 16 + (lane & 15)][(lane >> 4) * 8];
#pragma unroll
        for (int s = 0; s < 4; s++)
#pragma unroll
            for (int t = 0; t < 4; t++)
                acc[s][t] = __builtin_amdgcn_mfma_f32_16x16x32_bf16(af[s], bf[t], acc[s][t], 0, 0, 0);
    }

    // epilogue: C/D layout col=lane&15, row=(lane>>4)*4+reg
    const float* bp = bias ? (bias + (long)b * biasStride) : nullptr;
    float* Cf = (float*)Cv;
    unsigned short* Ch = (unsigned short*)Cv;
#pragma unroll
    for (int s = 0; s < 4; s++) {
#pragma unroll
        for (int t = 0; t < 4; t++) {
            const int col  = bn + wn * 64 + t * 16 + (lane & 15);
            const int row0 = bm + wm * 64 + s * 16 + (lane >> 4) * 4;
            const float bv = bp ? bp[col] : 0.f;
#pragma unroll
            for (int r = 0; r < 4; r++) {
                float v = alpha * acc[s][t][r] + bv;
                long off = (long)b * strideC + (long)(row0 + r) * ldc + col;
                if (OUT_BF16) Ch[off] = f2bf(v);
                else          Cf[off] = v;
            }
        }
    }
}

// ---------------------------------------------------------------------------
// fp32 -> bf16 cast (4 elems/thread)
// ---------------------------------------------------------------------------
__global__ void cast_kernel(const float* __restrict__ X, unsigned short* __restrict__ Y, long n) {
    long i = ((long)blockIdx.x * blockDim.x + threadIdx.x) * 4;
    if (i + 3 < n) {
        float4 v = *(const float4*)(X + i);
        Y[i] = f2bf(v.x); Y[i + 1] = f2bf(v.y); Y[i + 2] = f2bf(v.z); Y[i + 3] = f2bf(v.w);
    }
}

// fp32 [dim][dim] -> bf16 transposed [n][k]
__global__ void transpose_cast(const float* __restrict__ W, unsigned short* __restrict__ WT, int dim) {
    __shared__ float tile[32][33];
    const int bx = blockIdx.x * 32;  // n
    const int by = blockIdx.y * 32;  // k
    const int x = threadIdx.x, y = threadIdx.y;
#pragma unroll
    for (int i = 0; i < 32; i += 8)
        tile[y + i][x] = W[(long)(by + y + i) * dim + bx + x];
    __syncthreads();
#pragma unroll
    for (int i = 0; i < 32; i += 8)
        WT[(long)(bx + y + i) * dim + by + x] = f2bf(tile[x][y + i]);
}

__global__ void copy_bias3(const float* a, const float* b, const float* c, float* out) {
    int t = blockIdx.x * blockDim.x + threadIdx.x;   // 0..6143
    if (t < 2048) out[t] = a[t];
    else if (t < 4096) out[t] = b[t - 2048];
    else if (t < 6144) out[t] = c[t - 4096];
}

__global__ void fill_kernel(float* p, float v, long n) {
    long i = ((long)blockIdx.x * blockDim.x + threadIdx.x) * 4;
    if (i + 3 < n) { p[i] = v; p[i+1] = v; p[i+2] = v; p[i+3] = v; }
}

// ---------------------------------------------------------------------------
// Ranking path
// ---------------------------------------------------------------------------
__global__ void colmean_kernel(const float* __restrict__ hs, float* __restrict__ out) {
    int i = blockIdx.x * blockDim.x + threadIdx.x;   // column, 0..2047
    double acc = 0.0;
    for (int n = 0; n < 2048; n++) acc += (double)hs[(long)n * 2048 + i];
    out[i] = (float)(acc * (1.0 / 2048.0));
}

__global__ void qbar_kernel(const float* __restrict__ hsbar, const float* __restrict__ Wq,
                            const float* __restrict__ bq, float* __restrict__ qbar) {
    int j = blockIdx.x * blockDim.x + threadIdx.x;   // 0..2047
    double acc = (double)bq[j];
    for (int i = 0; i < 2048; i++) acc += (double)hsbar[i] * (double)Wq[(long)i * 2048 + j];
    qbar[j] = (float)acc;
}

__global__ void u_kernel(const float* __restrict__ Wk, const float* __restrict__ qbar,
                         float* __restrict__ U) {
    int t = blockIdx.x * blockDim.x + threadIdx.x;   // 0..32767 ; U[i*16+h]
    int h = t & 15, i = t >> 4;
    const float* w = Wk + (long)i * 2048 + h * 128;
    const float* q = qbar + h * 128;
    double acc = 0.0;
    for (int j = 0; j < 128; j++) acc += (double)w[j] * (double)q[j];
    U[t] = (float)acc;
}

// imp[h, m] = hs[m,:] . U[:,h]   (scale and constant dropped: rank-invariant)
__global__ __launch_bounds__(256) void imp_kernel(const float* __restrict__ hs,
                                                  const float* __restrict__ U,
                                                  float* __restrict__ imp) {
    __shared__ float row[2048];
    __shared__ float red[4][16];
    const int m = blockIdx.x, t = threadIdx.x;
    for (int i = t; i < 2048; i += 256) row[i] = hs[(long)m * 2048 + i];
    __syncthreads();
    float p[16];
#pragma unroll
    for (int h = 0; h < 16; h++) p[h] = 0.f;
    for (int i = t * 8; i < t * 8 + 8; i++) {
        const float v = row[i];
        const float* u = U + i * 16;
#pragma unroll
        for (int h = 0; h < 16; h++) p[h] += v * u[h];
    }
#pragma unroll
    for (int off = 32; off; off >>= 1)
#pragma unroll
        for (int h = 0; h < 16; h++) p[h] += __shfl_down(p[h], off);
    if ((t & 63) == 0)
#pragma unroll
        for (int h = 0; h < 16; h++) red[t >> 6][h] = p[h];
    __syncthreads();
    if (t < 16)
        imp[(long)t * 2048 + m] = red[0][t] + red[1][t] + red[2][t] + red[3][t];
}

// exact top-256 per head: binary search on order-preserving uint of fp32,
// ties at threshold taken lowest-index-first (jax.lax.top_k set semantics)
__global__ __launch_bounds__(256) void topk_kernel(const float* __restrict__ imp,
                                                   int* __restrict__ idx) {
    __shared__ unsigned uv[2048];
    __shared__ int wred[4];
    __shared__ int cnt_s;
    const int h = blockIdx.x, t = threadIdx.x;
    for (int m = t; m < 2048; m += 256) {
        unsigned u = __float_as_uint(imp[(long)h * 2048 + m]);
        uv[m] = (u & 0x80000000u) ? ~u : (u | 0x80000000u);
    }
    __syncthreads();
    unsigned cur = 0;
    for (int b = 31; b >= 0; b--) {
        unsigned cand = cur | (1u << b);
        int c = 0;
        for (int m = t; m < 2048; m += 256) c += (uv[m] >= cand) ? 1 : 0;
#pragma unroll
        for (int off = 32; off; off >>= 1) c += __shfl_down(c, off);
        if ((t & 63) == 0) wred[t >> 6] = c;
        __syncthreads();
        int tot = wred[0] + wred[1] + wred[2] + wred[3];
        if (tot >= 256) cur = cand;
        __syncthreads();
    }
    if (t == 0) cnt_s = 0;
    __syncthreads();
    for (int m = t; m < 2048; m += 256) {
        if (uv[m] > cur) { int p = atomicAdd(&cnt_s, 1); idx[h * 256 + p] = m; }
    }
    __syncthreads();
    if (t == 0) {
        int p = cnt_s;
        for (int m = 0; m < 2048 && p < 256; m++)
            if (uv[m] == cur) idx[h * 256 + p++] = m;
    }
}

// Ksel[h][j][d] = K[idx[h][j]][h*128+d] ; VselT[h][d][j] = V[idx[h][j]][h*128+d]
__global__ void gather_kernel(const unsigned short* __restrict__ Kb,
                              const unsigned short* __restrict__ Vb,
                              const int* __restrict__ idx,
                              unsigned short* __restrict__ Ksel,
                              unsigned short* __restrict__ VselT) {
    int t = blockIdx.x * blockDim.x + threadIdx.x;   // 0..524287
    {
        int d = t & 127, j = (t >> 7) & 255, h = t >> 15;
        int sr = idx[h * 256 + j];
        Ksel[t] = Kb[(long)sr * 2048 + h * 128 + d];
    }
    {
        int j = t & 255, d = (t >> 8) & 127, h = t >> 15;
        int sr = idx[h * 256 + j];
        VselT[t] = Vb[(long)sr * 2048 + h * 128 + d];
    }
}

// in-place row softmax over 256 bf16 scores
__global__ __launch_bounds__(256) void softmax_kernel(unsigned short* __restrict__ S) {
    __shared__ float red[8];
    const long r = blockIdx.x;
    const int t = threadIdx.x;
    unsigned short* row = S + r * 256;
    float v = bf2f(row[t]);
    float mx = v;
#pragma unroll
    for (int off = 32; off; off >>= 1) mx = fmaxf(mx, __shfl_xor(mx, off));
    if ((t & 63) == 0) red[t >> 6] = mx;
    __syncthreads();
    mx = fmaxf(fmaxf(red[0], red[1]), fmaxf(red[2], red[3]));
    float e = __expf(v - mx);
    float s = e;
#pragma unroll
    for (int off = 32; off; off >>= 1) s += __shfl_xor(s, off);
    if ((t & 63) == 0) red[4 + (t >> 6)] = s;
    __syncthreads();
    s = red[4] + red[5] + red[6] + red[7];
    row[t] = f2bf(e / s);
}

// ---------------------------------------------------------------------------
extern "C" void kernel_launch(void* const* d_in, const int* in_sizes, int n_in,
                              void* d_out, int out_size, void* d_ws, size_t ws_size,
                              hipStream_t stream)
{
    const float* hs = (const float*)d_in[0];
    const float* Wq = (const float*)d_in[1];
    const float* bq = (const float*)d_in[2];
    const float* Wk = (const float*)d_in[3];
    const float* bk = (const float*)d_in[4];
    const float* Wv = (const float*)d_in[5];
    const float* bv = (const float*)d_in[6];
    const float* Wo = (const float*)d_in[7];
    const float* bo = (const float*)d_in[8];

    char* ws = (char*)d_ws;
    size_t off = 0;
    auto alloc = [&](size_t b) -> void* {
        void* p = ws + off;
        off = (off + b + 255) & ~(size_t)255;
        return p;
    };
    unsigned short* HSb   = (unsigned short*)alloc(8388608);    // 2048x2048 bf16
    unsigned short* WqT   = (unsigned short*)alloc(8388608);    // [n][k]
    unsigned short* WkT   = (unsigned short*)alloc(8388608);
    unsigned short* WvT   = (unsigned short*)alloc(8388608);
    unsigned short* WoT   = (unsigned short*)alloc(8388608);
    unsigned short* Qb    = (unsigned short*)alloc(8388608);
    unsigned short* Kb    = (unsigned short*)alloc(8388608);
    unsigned short* Vb    = (unsigned short*)alloc(8388608);
    unsigned short* Att   = (unsigned short*)alloc(8388608);
    unsigned short* Sb    = (unsigned short*)alloc(16777216);   // [16][2048][256] bf16
    unsigned short* Ksel  = (unsigned short*)alloc(1048576);    // [16][256][128]
    unsigned short* VselT = (unsigned short*)alloc(1048576);    // [16][128][256]
    float* hsbar = (float*)alloc(8192);
    float* qbar  = (float*)alloc(8192);
    float* U     = (float*)alloc(131072);                        // [2048][16]
    float* imp   = (float*)alloc(131072);                        // [16][2048]
    int*   idx   = (int*)alloc(16384);                           // [16][256]
    float* bias3 = (float*)alloc(24576);                         // bq|bk|bv

    if (off > ws_size) {   // distinctive failure signature if workspace too small
        fill_kernel<<<4096, 256, 0, stream>>>((float*)d_out, 12345.0f, (long)out_size);
        return;
    }

    const float scale = 0.08838834764831845f;  // 1/sqrt(128)

    // --- prepasses (casts / transposes / biases) ---
    cast_kernel<<<4096, 256, 0, stream>>>(hs, HSb, 4194304);
    dim3 tb(32, 8);
    transpose_cast<<<dim3(64, 64), tb, 0, stream>>>(Wq, WqT, 2048);
    transpose_cast<<<dim3(64, 64), tb, 0, stream>>>(Wk, WkT, 2048);
    transpose_cast<<<dim3(64, 64), tb, 0, stream>>>(Wv, WvT, 2048);
    transpose_cast<<<dim3(64, 64), tb, 0, stream>>>(Wo, WoT, 2048);
    copy_bias3<<<24, 256, 0, stream>>>(bq, bk, bv, bias3);

    // --- ranking path (fp32/fp64 exact) ---
    colmean_kernel<<<8, 256, 0, stream>>>(hs, hsbar);
    qbar_kernel<<<8, 256, 0, stream>>>(hsbar, Wq, bq, qbar);
    u_kernel<<<128, 256, 0, stream>>>(Wk, qbar, U);
    imp_kernel<<<2048, 256, 0, stream>>>(hs, U, imp);
    topk_kernel<<<16, 256, 0, stream>>>(imp, idx);

    // --- QKV batched GEMM: [2048,2048]x[2048,2048] x3, bf16 out + bias ---
    gemm_bf16<true><<<dim3(16, 16, 3), 256, 0, stream>>>(
        HSb, 2048, 0, WqT, 2048, 4194304, Qb, 2048, 4194304,
        bias3, 2048, 2048, 2048, 2048, 1.0f);

    // --- gather selected K/V ---
    gather_kernel<<<2048, 256, 0, stream>>>(Kb, Vb, idx, Ksel, VselT);

    // --- S = scale * Q_h @ Ksel_h^T  : M=2048 N=256 K=128, batch 16 ---
    gemm_bf16<true><<<dim3(2, 16, 16), 256, 0, stream>>>(
        Qb, 2048, 128, Ksel, 128, 32768, Sb, 256, 524288,
        nullptr, 0, 2048, 256, 128, scale);

    // --- softmax rows of S (in place) ---
    softmax_kernel<<<32768, 256, 0, stream>>>(Sb);

    // --- O_h = P @ Vsel_h : M=2048 N=128 K=256, batch 16, write into Att cols ---
    gemm_bf16<true><<<dim3(1, 16, 16), 256, 0, stream>>>(
        Sb, 256, 524288, VselT, 256, 32768, Att, 2048, 128,
        nullptr, 0, 2048, 128, 256, 1.0f);

    // --- out = Att @ Wo + bo (fp32) ---
    gemm_bf16<false><<<dim3(16, 16, 1), 256, 0, stream>>>(
        Att, 2048, 0, WoT, 2048, 0, d_out, 2048, 0,
        bo, 0, 2048, 2048, 2048, 1.0f);
}

// Round 2
// 404.234 us; speedup vs baseline: 1.6789x; 1.6789x over previous
//
#include <hip/hip_runtime.h>

// ---------------------------------------------------------------------------
// SparseAttention on MI355X (gfx950)
// hidden=2048, heads=16, d=128, topk=256, N=2048, B=1
//
// Ranking path (fp32/fp64, exact):  imp[h,m] = hs[m,:] . U[:,h]
//   where U[i,h] = sum_{j in head h} Wk[i,j]*qbar[j],  qbar = mean_n(HS) @ Wq + bq
// Value path (bf16 MFMA, m97 structure): QKV GEMMs, gather, QK_sel, softmax, PV, O.
// ---------------------------------------------------------------------------

typedef __attribute__((ext_vector_type(8))) short bf16x8;
typedef __attribute__((ext_vector_type(4))) float f32x4;

__device__ __forceinline__ unsigned short f2bf(float x) {
    unsigned u = __float_as_uint(x);
    u += 0x7fffu + ((u >> 16) & 1u);      // round to nearest even
    return (unsigned short)(u >> 16);
}
__device__ __forceinline__ float bf2f(unsigned short h) {
    return __uint_as_float(((unsigned)h) << 16);
}

__device__ __forceinline__ void load_lds16(const unsigned short* g, unsigned short* l) {
    __builtin_amdgcn_global_load_lds(
        (const __attribute__((address_space(1))) unsigned int*)g,
        (__attribute__((address_space(3))) unsigned int*)l,
        16, 0, 0);
}

// ---------------------------------------------------------------------------
// Generic bf16 MFMA GEMM:  C[b,m,n] = alpha * sum_k A[b,m,k]*Bt[b,n,k] (+ bias[b,n])
// A, Bt bf16 (ushort bits); C fp32 or bf16. Tile 128x128, BK=32, 256 threads.
// ---------------------------------------------------------------------------
template <bool OUT_BF16>
__global__ __launch_bounds__(256) void gemm_bf16(
    const unsigned short* __restrict__ A, long lda, long strideA,
    const unsigned short* __restrict__ Bt, long ldb, long strideB,
    void* __restrict__ Cv, long ldc, long strideC,
    const float* __restrict__ bias, long biasStride,
    int M, int N, int K, float alpha)
{
    __shared__ __align__(16) unsigned short As[128][32];   // 8 KB
    __shared__ __align__(16) unsigned short Bs[128][32];   // 8 KB (Bt rows: [n][k])

    const int tid  = threadIdx.x;
    const int lane = tid & 63;
    const int wave = tid >> 6;                 // 0..3
    const int wm = wave >> 1, wn = wave & 1;   // 2x2 wave grid, each wave 64x64

    const int bm = blockIdx.y * 128;
    const int bn = blockIdx.x * 128;
    const int b  = blockIdx.z;

    const unsigned short* Ab = A  + (long)b * strideA;
    const unsigned short* Bb = Bt + (long)b * strideB;

    f32x4 acc[4][4];
#pragma unroll
    for (int i = 0; i < 4; i++)
#pragma unroll
        for (int j = 0; j < 4; j++) acc[i][j] = f32x4{0.f, 0.f, 0.f, 0.f};

    const int rg = wave * 32;          // this wave stages rows [rg, rg+32) of each tile
    const int lr = lane >> 2;          // 0..15 : row within 16-row group
    const int lc = (lane & 3) * 8;     // 0,8,16,24 : bf16 col offset (16B chunk)

    for (int k0 = 0; k0 < K; k0 += 32) {
        __syncthreads();   // previous iteration's frag reads must finish
#pragma unroll
        for (int q = 0; q < 2; q++) {
            const unsigned short* g = Ab + (long)(bm + rg + q * 16 + lr) * lda + k0 + lc;
            load_lds16(g, &As[rg + q * 16][0]);
        }
#pragma unroll
        for (int q = 0; q < 2; q++) {
            const unsigned short* g = Bb + (long)(bn + rg + q * 16 + lr) * ldb + k0 + lc;
            load_lds16(g, &Bs[rg + q * 16][0]);
        }
        __syncthreads();

        bf16x8 af[4], bf[4];
#pragma unroll
        for (int s = 0; s < 4; s++)
            af[s] = *(const bf16x8*)&As[wm * 64 + s * 16 + (lane & 15)][(lane >> 4) * 8];
#pragma unroll
        for (int t = 0; t < 4; t++)
            bf[t] = *(const bf16x8*)&Bs[wn * 64 + t * 16 + (lane & 15)][(lane >> 4) * 8];
#pragma unroll
        for (int s = 0; s < 4; s++)
#pragma unroll
            for (int t = 0; t < 4; t++)
                acc[s][t] = __builtin_amdgcn_mfma_f32_16x16x32_bf16(af[s], bf[t], acc[s][t], 0, 0, 0);
    }

    // epilogue: C/D layout col=lane&15, row=(lane>>4)*4+reg
    const float* bp = bias ? (bias + (long)b * biasStride) : nullptr;
    float* Cf = (float*)Cv;
    unsigned short* Ch = (unsigned short*)Cv;
#pragma unroll
    for (int s = 0; s < 4; s++) {
#pragma unroll
        for (int t = 0; t < 4; t++) {
            const int col  = bn + wn * 64 + t * 16 + (lane & 15);
            const int row0 = bm + wm * 64 + s * 16 + (lane >> 4) * 4;
            const float bv = bp ? bp[col] : 0.f;
#pragma unroll
            for (int r = 0; r < 4; r++) {
                float v = alpha * acc[s][t][r] + bv;
                long off = (long)b * strideC + (long)(row0 + r) * ldc + col;
                if (OUT_BF16) Ch[off] = f2bf(v);
                else          Cf[off] = v;
            }
        }
    }
}

// ---------------------------------------------------------------------------
// fp32 -> bf16 cast (4 elems/thread)
// ---------------------------------------------------------------------------
__global__ void cast_kernel(const float* __restrict__ X, unsigned short* __restrict__ Y, long n) {
    long i = ((long)blockIdx.x * blockDim.x + threadIdx.x) * 4;
    if (i + 3 < n) {
        float4 v = *(const float4*)(X + i);
        Y[i] = f2bf(v.x); Y[i + 1] = f2bf(v.y); Y[i + 2] = f2bf(v.z); Y[i + 3] = f2bf(v.w);
    }
}

// fp32 [dim][dim] -> bf16 transposed [n][k]
__global__ void transpose_cast(const float* __restrict__ W, unsigned short* __restrict__ WT, int dim) {
    __shared__ float tile[32][33];
    const int bx = blockIdx.x * 32;  // n
    const int by = blockIdx.y * 32;  // k
    const int x = threadIdx.x, y = threadIdx.y;
#pragma unroll
    for (int i = 0; i < 32; i += 8)
        tile[y + i][x] = W[(long)(by + y + i) * dim + bx + x];
    __syncthreads();
#pragma unroll
    for (int i = 0; i < 32; i += 8)
        WT[(long)(bx + y + i) * dim + by + x] = f2bf(tile[x][y + i]);
}

__global__ void copy_bias3(const float* a, const float* b, const float* c, float* out) {
    int t = blockIdx.x * blockDim.x + threadIdx.x;   // 0..6143
    if (t < 2048) out[t] = a[t];
    else if (t < 4096) out[t] = b[t - 2048];
    else if (t < 6144) out[t] = c[t - 4096];
}

__global__ void fill_kernel(float* p, float v, long n) {
    long i = ((long)blockIdx.x * blockDim.x + threadIdx.x) * 4;
    if (i + 3 < n) { p[i] = v; p[i+1] = v; p[i+2] = v; p[i+3] = v; }
}

// ---------------------------------------------------------------------------
// Ranking path (restructured for full-chip parallelism, deterministic order)
// ---------------------------------------------------------------------------

// stage 1: part[g][col] = sum over rows [g*32, g*32+32) of hs[row][col], double
__global__ __launch_bounds__(256) void colsum_part(const float* __restrict__ hs,
                                                   double* __restrict__ part) {
    const int col = blockIdx.x * 256 + threadIdx.x;
    const int r0  = blockIdx.y * 32;
    double a = 0.0;
#pragma unroll 4
    for (int r = 0; r < 32; r++) a += (double)hs[(long)(r0 + r) * 2048 + col];
    part[(long)blockIdx.y * 2048 + col] = a;
}

// stage 2: hsbar[col] = (1/2048) * sum_g part[g][col]
__global__ void colsum_fin(const double* __restrict__ part, float* __restrict__ hsbar) {
    const int col = blockIdx.x * 64 + threadIdx.x;
    double s = 0.0;
#pragma unroll 4
    for (int g = 0; g < 64; g++) s += part[(long)g * 2048 + col];
    hsbar[col] = (float)(s * (1.0 / 2048.0));
}

// stage 1: partq[g][j] = sum over i in [g*32, g*32+32) hsbar[i] * Wq[i][j]
__global__ __launch_bounds__(256) void qsum_part(const float* __restrict__ hsbar,
                                                 const float* __restrict__ Wq,
                                                 double* __restrict__ partq) {
    const int j  = blockIdx.x * 256 + threadIdx.x;
    const int i0 = blockIdx.y * 32;
    double a = 0.0;
#pragma unroll 4
    for (int r = 0; r < 32; r++)
        a += (double)hsbar[i0 + r] * (double)Wq[(long)(i0 + r) * 2048 + j];
    partq[(long)blockIdx.y * 2048 + j] = a;
}

__global__ void qsum_fin(const double* __restrict__ partq, const float* __restrict__ bq,
                         float* __restrict__ qbar) {
    const int j = blockIdx.x * 64 + threadIdx.x;
    double s = (double)bq[j];
#pragma unroll 4
    for (int g = 0; g < 64; g++) s += partq[(long)g * 2048 + j];
    qbar[j] = (float)s;
}

// U[i][h] = dot(Wk[i, h*128:(h+1)*128], qbar[h*128:(h+1)*128])
// one block per row i; coalesced float4 reads; half-wave (32-lane) reduce per head
__global__ __launch_bounds__(256) void u_kernel(const float* __restrict__ Wk,
                                                const float* __restrict__ qbar,
                                                float* __restrict__ U) {
    const int i = blockIdx.x, t = threadIdx.x;
#pragma unroll
    for (int r = 0; r < 2; r++) {
        const int e = r * 1024 + t * 4;
        float4 w = *(const float4*)(Wk + (long)i * 2048 + e);
        float4 q = *(const float4*)(qbar + e);
        float a = w.x * q.x + w.y * q.y + w.z * q.z + w.w * q.w;
#pragma unroll
        for (int off = 16; off; off >>= 1) a += __shfl_xor(a, off);
        if ((t & 31) == 0) U[(long)i * 16 + r * 8 + (t >> 5)] = a;
    }
}

// imp[h, m] = hs[m,:] . U[:,h]   (scale and constant dropped: rank-invariant)
__global__ __launch_bounds__(256) void imp_kernel(const float* __restrict__ hs,
                                                  const float* __restrict__ U,
                                                  float* __restrict__ imp) {
    __shared__ float row[2048];
    __shared__ float red[4][16];
    const int m = blockIdx.x, t = threadIdx.x;
    for (int i = t; i < 2048; i += 256) row[i] = hs[(long)m * 2048 + i];
    __syncthreads();
    float p[16];
#pragma unroll
    for (int h = 0; h < 16; h++) p[h] = 0.f;
    for (int i = t * 8; i < t * 8 + 8; i++) {
        const float v = row[i];
        const float* u = U + i * 16;
#pragma unroll
        for (int h = 0; h < 16; h++) p[h] += v * u[h];
    }
#pragma unroll
    for (int off = 32; off; off >>= 1)
#pragma unroll
        for (int h = 0; h < 16; h++) p[h] += __shfl_down(p[h], off);
    if ((t & 63) == 0)
#pragma unroll
        for (int h = 0; h < 16; h++) red[t >> 6][h] = p[h];
    __syncthreads();
    if (t < 16)
        imp[(long)t * 2048 + m] = red[0][t] + red[1][t] + red[2][t] + red[3][t];
}

// exact top-256 per head: one WAVE per head, values register-resident,
// ballot+popcount counting (no barriers, no LDS). Ties lowest-index-first.
__global__ __launch_bounds__(64) void topk_kernel(const float* __restrict__ imp,
                                                  int* __restrict__ idx) {
    const int h = blockIdx.x;
    const int lane = threadIdx.x;
    unsigned u[32];
#pragma unroll
    for (int r = 0; r < 32; r++) {
        unsigned x = __float_as_uint(imp[(long)h * 2048 + r * 64 + lane]);
        u[r] = (x & 0x80000000u) ? ~x : (x | 0x80000000u);
    }
    unsigned cur = 0;
    for (int b = 31; b >= 0; b--) {
        const unsigned cand = cur | (1u << b);
        int tot = 0;
#pragma unroll
        for (int r = 0; r < 32; r++)
            tot += (int)__popcll(__ballot(u[r] >= cand));
        if (tot >= 256) cur = cand;   // wave-uniform
    }
    const unsigned long long below = (1ull << lane) - 1ull;
    int base = 0;
    // strictly greater, stable index order (r asc, lane asc)
#pragma unroll
    for (int r = 0; r < 32; r++) {
        const bool q = u[r] > cur;
        const unsigned long long m = __ballot(q);
        if (q) idx[h * 256 + base + (int)__popcll(m & below)] = r * 64 + lane;
        base += (int)__popcll(m);
    }
    // ties at threshold, lowest index first, until 256 filled
#pragma unroll
    for (int r = 0; r < 32; r++) {
        const bool q = (u[r] == cur);
        const unsigned long long m = __ballot(q);
        if (q) {
            const int pos = base + (int)__popcll(m & below);
            if (pos < 256) idx[h * 256 + pos] = r * 64 + lane;
        }
        base += (int)__popcll(m);
        if (base >= 256) break;
    }
}

// Ksel[h][j][d] = K[idx[h][j]][h*128+d] ; VselT[h][d][j] = V[idx[h][j]][h*128+d]
__global__ void gather_kernel(const unsigned short* __restrict__ Kb,
                              const unsigned short* __restrict__ Vb,
                              const int* __restrict__ idx,
                              unsigned short* __restrict__ Ksel,
                              unsigned short* __restrict__ VselT) {
    int t = blockIdx.x * blockDim.x + threadIdx.x;   // 0..524287
    {
        int d = t & 127, j = (t >> 7) & 255, h = t >> 15;
        int sr = idx[h * 256 + j];
        Ksel[t] = Kb[(long)sr * 2048 + h * 128 + d];
    }
    {
        int j = t & 255, d = (t >> 8) & 127, h = t >> 15;
        int sr = idx[h * 256 + j];
        VselT[t] = Vb[(long)sr * 2048 + h * 128 + d];
    }
}

// in-place row softmax over 256 bf16 scores
__global__ __launch_bounds__(256) void softmax_kernel(unsigned short* __restrict__ S) {
    __shared__ float red[8];
    const long r = blockIdx.x;
    const int t = threadIdx.x;
    unsigned short* row = S + r * 256;
    float v = bf2f(row[t]);
    float mx = v;
#pragma unroll
    for (int off = 32; off; off >>= 1) mx = fmaxf(mx, __shfl_xor(mx, off));
    if ((t & 63) == 0) red[t >> 6] = mx;
    __syncthreads();
    mx = fmaxf(fmaxf(red[0], red[1]), fmaxf(red[2], red[3]));
    float e = __expf(v - mx);
    float s = e;
#pragma unroll
    for (int off = 32; off; off >>= 1) s += __shfl_xor(s, off);
    if ((t & 63) == 0) red[4 + (t >> 6)] = s;
    __syncthreads();
    s = red[4] + red[5] + red[6] + red[7];
    row[t] = f2bf(e / s);
}

// ---------------------------------------------------------------------------
extern "C" void kernel_launch(void* const* d_in, const int* in_sizes, int n_in,
                              void* d_out, int out_size, void* d_ws, size_t ws_size,
                              hipStream_t stream)
{
    const float* hs = (const float*)d_in[0];
    const float* Wq = (const float*)d_in[1];
    const float* bq = (const float*)d_in[2];
    const float* Wk = (const float*)d_in[3];
    const float* bk = (const float*)d_in[4];
    const float* Wv = (const float*)d_in[5];
    const float* bv = (const float*)d_in[6];
    const float* Wo = (const float*)d_in[7];
    const float* bo = (const float*)d_in[8];

    char* ws = (char*)d_ws;
    size_t off = 0;
    auto alloc = [&](size_t b) -> void* {
        void* p = ws + off;
        off = (off + b + 255) & ~(size_t)255;
        return p;
    };
    unsigned short* HSb   = (unsigned short*)alloc(8388608);    // 2048x2048 bf16
    unsigned short* WqT   = (unsigned short*)alloc(8388608);    // [n][k]
    unsigned short* WkT   = (unsigned short*)alloc(8388608);
    unsigned short* WvT   = (unsigned short*)alloc(8388608);
    unsigned short* WoT   = (unsigned short*)alloc(8388608);
    unsigned short* Qb    = (unsigned short*)alloc(8388608);
    unsigned short* Kb    = (unsigned short*)alloc(8388608);
    unsigned short* Vb    = (unsigned short*)alloc(8388608);
    unsigned short* Att   = (unsigned short*)alloc(8388608);
    unsigned short* Sb    = (unsigned short*)alloc(16777216);   // [16][2048][256] bf16
    unsigned short* Ksel  = (unsigned short*)alloc(1048576);    // [16][256][128]
    unsigned short* VselT = (unsigned short*)alloc(1048576);    // [16][128][256]
    double* part  = (double*)alloc(1048576);                    // [64][2048] partials (reused)
    float* hsbar = (float*)alloc(8192);
    float* qbar  = (float*)alloc(8192);
    float* U     = (float*)alloc(131072);                        // [2048][16]
    float* imp   = (float*)alloc(131072);                        // [16][2048]
    int*   idx   = (int*)alloc(16384);                           // [16][256]
    float* bias3 = (float*)alloc(24576);                         // bq|bk|bv

    if (off > ws_size) {   // distinctive failure signature if workspace too small
        fill_kernel<<<4096, 256, 0, stream>>>((float*)d_out, 12345.0f, (long)out_size);
        return;
    }

    const float scale = 0.08838834764831845f;  // 1/sqrt(128)

    // --- prepasses (casts / transposes / biases) ---
    cast_kernel<<<4096, 256, 0, stream>>>(hs, HSb, 4194304);
    dim3 tb(32, 8);
    transpose_cast<<<dim3(64, 64), tb, 0, stream>>>(Wq, WqT, 2048);
    transpose_cast<<<dim3(64, 64), tb, 0, stream>>>(Wk, WkT, 2048);
    transpose_cast<<<dim3(64, 64), tb, 0, stream>>>(Wv, WvT, 2048);
    transpose_cast<<<dim3(64, 64), tb, 0, stream>>>(Wo, WoT, 2048);
    copy_bias3<<<24, 256, 0, stream>>>(bq, bk, bv, bias3);

    // --- ranking path (exact, deterministic) ---
    colsum_part<<<dim3(8, 64), 256, 0, stream>>>(hs, part);
    colsum_fin<<<32, 64, 0, stream>>>(part, hsbar);
    qsum_part<<<dim3(8, 64), 256, 0, stream>>>(hsbar, Wq, part);
    qsum_fin<<<32, 64, 0, stream>>>(part, bq, qbar);
    u_kernel<<<2048, 256, 0, stream>>>(Wk, qbar, U);
    imp_kernel<<<2048, 256, 0, stream>>>(hs, U, imp);
    topk_kernel<<<16, 64, 0, stream>>>(imp, idx);

    // --- QKV batched GEMM: [2048,2048]x[2048,2048] x3, bf16 out + bias ---
    gemm_bf16<true><<<dim3(16, 16, 3), 256, 0, stream>>>(
        HSb, 2048, 0, WqT, 2048, 4194304, Qb, 2048, 4194304,
        bias3, 2048, 2048, 2048, 2048, 1.0f);

    // --- gather selected K/V ---
    gather_kernel<<<2048, 256, 0, stream>>>(Kb, Vb, idx, Ksel, VselT);

    // --- S = scale * Q_h @ Ksel_h^T  : M=2048 N=256 K=128, batch 16 ---
    gemm_bf16<true><<<dim3(2, 16, 16), 256, 0, stream>>>(
        Qb, 2048, 128, Ksel, 128, 32768, Sb, 256, 524288,
        nullptr, 0, 2048, 256, 128, scale);

    // --- softmax rows of S (in place) ---
    softmax_kernel<<<32768, 256, 0, stream>>>(Sb);

    // --- O_h = P @ Vsel_h : M=2048 N=128 K=256, batch 16, write into Att cols ---
    gemm_bf16<true><<<dim3(1, 16, 16), 256, 0, stream>>>(
        Sb, 256, 524288, VselT, 256, 32768, Att, 2048, 128,
        nullptr, 0, 2048, 128, 256, 1.0f);

    // --- out = Att @ Wo + bo (fp32) ---
    gemm_bf16<false><<<dim3(16, 16, 1), 256, 0, stream>>>(
        Att, 2048, 0, WoT, 2048, 0, d_out, 2048, 0,
        bo, 0, 2048, 2048, 2048, 1.0f);
}

// Round 3
// 338.133 us; speedup vs baseline: 2.0071x; 1.1955x over previous
//
#include <hip/hip_runtime.h>

// ---------------------------------------------------------------------------
// SparseAttention on MI355X (gfx950)
// hidden=2048, heads=16, d=128, topk=256, N=2048, B=1
//
// Ranking path (fp32/fp64, exact):  imp[h,m] = hs[m,:] . U[:,h]
//   where U[i,h] = sum_{j in head h} Wk[i,j]*qbar[j],  qbar = mean_n(HS) @ Wq + bq
// Value path (bf16 MFMA): QKV GEMM, gather, fused flash-style attention, O GEMM.
// ---------------------------------------------------------------------------

typedef __attribute__((ext_vector_type(8))) short bf16x8;
typedef __attribute__((ext_vector_type(4))) float f32x4;

__device__ __forceinline__ unsigned short f2bf(float x) {
    unsigned u = __float_as_uint(x);
    u += 0x7fffu + ((u >> 16) & 1u);      // round to nearest even
    return (unsigned short)(u >> 16);
}

__device__ __forceinline__ void load_lds16(const unsigned short* g, unsigned short* l) {
    __builtin_amdgcn_global_load_lds(
        (const __attribute__((address_space(1))) unsigned int*)g,
        (__attribute__((address_space(3))) unsigned int*)l,
        16, 0, 0);
}

struct Bias3 { const float* p0; const float* p1; const float* p2; };
struct Ptr4  { const float* p[4]; };

// ---------------------------------------------------------------------------
// bf16 MFMA GEMM:  C[b,m,n] = alpha * sum_k A[b,m,k]*Bt[b,n,k] (+ bias_b[n])
// Tile 128 x TN (TN = 128 or 64), BK=32, 256 threads (2x2 waves).
// ---------------------------------------------------------------------------
template <int TN, bool OUT_BF16>
__global__ __launch_bounds__(256) void gemm_bf16(
    const unsigned short* __restrict__ A, long lda, long strideA,
    const unsigned short* __restrict__ Bt, long ldb, long strideB,
    void* __restrict__ Cv, long ldc, long strideC,
    Bias3 bias, int K, float alpha)
{
    constexpr int SN = TN / 32;                       // 16-col tiles per wave
    __shared__ __align__(16) unsigned short As[128][32];
    __shared__ __align__(16) unsigned short Bs[TN][32];

    const int tid  = threadIdx.x;
    const int lane = tid & 63;
    const int wave = tid >> 6;
    const int wm = wave >> 1, wn = wave & 1;

    const int bm = blockIdx.y * 128;
    const int bn = blockIdx.x * TN;
    const int b  = blockIdx.z;

    const unsigned short* Ab = A  + (long)b * strideA;
    const unsigned short* Bb = Bt + (long)b * strideB;

    f32x4 acc[4][SN];
#pragma unroll
    for (int i = 0; i < 4; i++)
#pragma unroll
        for (int j = 0; j < SN; j++) acc[i][j] = f32x4{0.f, 0.f, 0.f, 0.f};

    const int lr = lane >> 2;          // 0..15 row within 16-row staging group
    const int lc = (lane & 3) * 8;     // bf16 col offset (16B chunk)

    for (int k0 = 0; k0 < K; k0 += 32) {
        __syncthreads();
#pragma unroll
        for (int r0 = wave * 16; r0 < 128; r0 += 64)
            load_lds16(Ab + (long)(bm + r0 + lr) * lda + k0 + lc, &As[r0][0]);
#pragma unroll
        for (int r0 = wave * 16; r0 < TN; r0 += 64)
            load_lds16(Bb + (long)(bn + r0 + lr) * ldb + k0 + lc, &Bs[r0][0]);
        __syncthreads();

        bf16x8 af[4], bf[SN];
#pragma unroll
        for (int s = 0; s < 4; s++)
            af[s] = *(const bf16x8*)&As[wm * 64 + s * 16 + (lane & 15)][(lane >> 4) * 8];
#pragma unroll
        for (int t = 0; t < SN; t++)
            bf[t] = *(const bf16x8*)&Bs[wn * (TN / 2) + t * 16 + (lane & 15)][(lane >> 4) * 8];
#pragma unroll
        for (int s = 0; s < 4; s++)
#pragma unroll
            for (int t = 0; t < SN; t++)
                acc[s][t] = __builtin_amdgcn_mfma_f32_16x16x32_bf16(af[s], bf[t], acc[s][t], 0, 0, 0);
    }

    // epilogue: C/D layout col=lane&15, row=(lane>>4)*4+reg
    const float* bp = (b == 0) ? bias.p0 : (b == 1) ? bias.p1 : bias.p2;
    float* Cf = (float*)Cv;
    unsigned short* Ch = (unsigned short*)Cv;
#pragma unroll
    for (int s = 0; s < 4; s++) {
#pragma unroll
        for (int t = 0; t < SN; t++) {
            const int col  = bn + wn * (TN / 2) + t * 16 + (lane & 15);
            const int row0 = bm + wm * 64 + s * 16 + (lane >> 4) * 4;
            const float bv = bp ? bp[col] : 0.f;
#pragma unroll
            for (int r = 0; r < 4; r++) {
                float v = alpha * acc[s][t][r] + bv;
                long off = (long)b * strideC + (long)(row0 + r) * ldc + col;
                if (OUT_BF16) Ch[off] = f2bf(v);
                else          Cf[off] = v;
            }
        }
    }
}

// ---------------------------------------------------------------------------
// Fused attention: per (m-tile, head): S = scale*Q Ksel^T (fp32 regs),
// in-wave softmax, P(bf16)->LDS, O = P Vsel * (1/l), write to Att.
// ---------------------------------------------------------------------------
__global__ __launch_bounds__(256, 1) void attn_kernel(
    const unsigned short* __restrict__ Qb,     // [2048][2048] (token, h*128+d)
    const unsigned short* __restrict__ Ksel,   // [16][256][128]
    const unsigned short* __restrict__ VselT,  // [16][128][256]
    unsigned short* __restrict__ Att)          // [2048][2048]
{
    __shared__ __align__(16) unsigned short Qs[128][32];
    __shared__ __align__(16) unsigned short Ks[256][32];
    __shared__ __align__(16) unsigned short Vs[128][32];
    __shared__ __align__(16) unsigned short Ps[128][264];   // pad 8 shorts
    __shared__ float linv[128];

    const int tid  = threadIdx.x;
    const int lane = tid & 63;
    const int wave = tid >> 6;
    const int bm = blockIdx.x * 128;
    const int h  = blockIdx.y;
    const int lr = lane >> 2, lc = (lane & 3) * 8;

    const unsigned short* Kh = Ksel  + h * 32768;
    const unsigned short* Vh = VselT + h * 32768;

    // ---- phase 1: S tile 128x256, wave owns rows wave*32..+32 (4x1 layout)
    f32x4 acc[2][16];
#pragma unroll
    for (int s = 0; s < 2; s++)
#pragma unroll
        for (int t = 0; t < 16; t++) acc[s][t] = f32x4{0.f, 0.f, 0.f, 0.f};

    for (int k0 = 0; k0 < 128; k0 += 32) {
        __syncthreads();
#pragma unroll
        for (int r0 = wave * 16; r0 < 128; r0 += 64)
            load_lds16(Qb + (long)(bm + r0 + lr) * 2048 + h * 128 + k0 + lc, &Qs[r0][0]);
#pragma unroll
        for (int r0 = wave * 16; r0 < 256; r0 += 64)
            load_lds16(Kh + (r0 + lr) * 128 + k0 + lc, &Ks[r0][0]);
        __syncthreads();

        bf16x8 af[2];
#pragma unroll
        for (int s = 0; s < 2; s++)
            af[s] = *(const bf16x8*)&Qs[wave * 32 + s * 16 + (lane & 15)][(lane >> 4) * 8];
#pragma unroll
        for (int t = 0; t < 16; t++) {
            bf16x8 bf = *(const bf16x8*)&Ks[t * 16 + (lane & 15)][(lane >> 4) * 8];
            acc[0][t] = __builtin_amdgcn_mfma_f32_16x16x32_bf16(af[0], bf, acc[0][t], 0, 0, 0);
            acc[1][t] = __builtin_amdgcn_mfma_f32_16x16x32_bf16(af[1], bf, acc[1][t], 0, 0, 0);
        }
    }

    // ---- phase 2: in-wave softmax over 256 cols; P = exp(scale*(s-max)), bf16
    const float se = 0.08838834764831845f * 1.4426950408889634f;  // scale*log2(e)
#pragma unroll
    for (int s = 0; s < 2; s++) {
#pragma unroll
        for (int r = 0; r < 4; r++) {
            float mx = -3.0e38f;
#pragma unroll
            for (int t = 0; t < 16; t++) mx = fmaxf(mx, acc[s][t][r]);
#pragma unroll
            for (int off = 1; off < 16; off <<= 1) mx = fmaxf(mx, __shfl_xor(mx, off));
            float sum = 0.f;
#pragma unroll
            for (int t = 0; t < 16; t++) {
                float p = exp2f((acc[s][t][r] - mx) * se);
                acc[s][t][r] = p;
                sum += p;
            }
#pragma unroll
            for (int off = 1; off < 16; off <<= 1) sum += __shfl_xor(sum, off);
            const int row = wave * 32 + s * 16 + (lane >> 4) * 4 + r;
#pragma unroll
            for (int t = 0; t < 16; t++)
                Ps[row][t * 16 + (lane & 15)] = f2bf(acc[s][t][r]);
            if ((lane & 15) == 0) linv[row] = 1.0f / sum;
        }
    }

    // ---- phase 3: O = P @ Vsel, 2x2 waves over 128x128
    const int wm2 = wave >> 1, wn2 = wave & 1;
    f32x4 acc2[4][4];
#pragma unroll
    for (int i = 0; i < 4; i++)
#pragma unroll
        for (int j = 0; j < 4; j++) acc2[i][j] = f32x4{0.f, 0.f, 0.f, 0.f};

    for (int j0 = 0; j0 < 256; j0 += 32) {
        __syncthreads();   // (also makes Ps/linv visible on first iteration)
#pragma unroll
        for (int r0 = wave * 16; r0 < 128; r0 += 64)
            load_lds16(Vh + (r0 + lr) * 256 + j0 + lc, &Vs[r0][0]);
        __syncthreads();

        bf16x8 af2[4], bf2[4];
#pragma unroll
        for (int s2 = 0; s2 < 4; s2++)
            af2[s2] = *(const bf16x8*)&Ps[wm2 * 64 + s2 * 16 + (lane & 15)][j0 + (lane >> 4) * 8];
#pragma unroll
        for (int t2 = 0; t2 < 4; t2++)
            bf2[t2] = *(const bf16x8*)&Vs[wn2 * 64 + t2 * 16 + (lane & 15)][(lane >> 4) * 8];
#pragma unroll
        for (int s2 = 0; s2 < 4; s2++)
#pragma unroll
            for (int t2 = 0; t2 < 4; t2++)
                acc2[s2][t2] = __builtin_amdgcn_mfma_f32_16x16x32_bf16(af2[s2], bf2[t2], acc2[s2][t2], 0, 0, 0);
    }

    // ---- epilogue: divide by row sum, write Att[token][h*128+d]
#pragma unroll
    for (int s2 = 0; s2 < 4; s2++) {
#pragma unroll
        for (int t2 = 0; t2 < 4; t2++) {
            const int d = wn2 * 64 + t2 * 16 + (lane & 15);
#pragma unroll
            for (int r = 0; r < 4; r++) {
                const int row = wm2 * 64 + s2 * 16 + (lane >> 4) * 4 + r;
                float v = acc2[s2][t2][r] * linv[row];
                Att[(long)(bm + row) * 2048 + h * 128 + d] = f2bf(v);
            }
        }
    }
}

// ---------------------------------------------------------------------------
// fp32 [dim][dim] -> bf16 transposed [n][k], 4 matrices batched over z
// ---------------------------------------------------------------------------
__global__ void transpose_cast4(Ptr4 srcs, unsigned short* __restrict__ WT4) {
    __shared__ float tile[32][33];
    const float* W = srcs.p[blockIdx.z];
    unsigned short* WT = WT4 + (long)blockIdx.z * 4194304;
    const int bx = blockIdx.x * 32;  // n
    const int by = blockIdx.y * 32;  // k
    const int x = threadIdx.x, y = threadIdx.y;
#pragma unroll
    for (int i = 0; i < 32; i += 8)
        tile[y + i][x] = W[(long)(by + y + i) * 2048 + bx + x];
    __syncthreads();
#pragma unroll
    for (int i = 0; i < 32; i += 8)
        WT[(long)(bx + y + i) * 2048 + by + x] = f2bf(tile[x][y + i]);
}

__global__ void fill_kernel(float* p, float v, long n) {
    long i = ((long)blockIdx.x * blockDim.x + threadIdx.x) * 4;
    if (i + 3 < n) { p[i] = v; p[i+1] = v; p[i+2] = v; p[i+3] = v; }
}

// ---------------------------------------------------------------------------
// Ranking path
// ---------------------------------------------------------------------------
__global__ __launch_bounds__(256) void colsum_part(const float* __restrict__ hs,
                                                   double* __restrict__ part) {
    const int col = blockIdx.x * 256 + threadIdx.x;
    const int r0  = blockIdx.y * 32;
    double a = 0.0;
#pragma unroll 4
    for (int r = 0; r < 32; r++) a += (double)hs[(long)(r0 + r) * 2048 + col];
    part[(long)blockIdx.y * 2048 + col] = a;
}

__global__ void colsum_fin(const double* __restrict__ part, float* __restrict__ hsbar) {
    const int col = blockIdx.x * 64 + threadIdx.x;
    double s = 0.0;
#pragma unroll 4
    for (int g = 0; g < 64; g++) s += part[(long)g * 2048 + col];
    hsbar[col] = (float)(s * (1.0 / 2048.0));
}

__global__ __launch_bounds__(256) void qsum_part(const float* __restrict__ hsbar,
                                                 const float* __restrict__ Wq,
                                                 double* __restrict__ partq) {
    const int j  = blockIdx.x * 256 + threadIdx.x;
    const int i0 = blockIdx.y * 32;
    double a = 0.0;
#pragma unroll 4
    for (int r = 0; r < 32; r++)
        a += (double)hsbar[i0 + r] * (double)Wq[(long)(i0 + r) * 2048 + j];
    partq[(long)blockIdx.y * 2048 + j] = a;
}

__global__ void qsum_fin(const double* __restrict__ partq, const float* __restrict__ bq,
                         float* __restrict__ qbar) {
    const int j = blockIdx.x * 64 + threadIdx.x;
    double s = (double)bq[j];
#pragma unroll 4
    for (int g = 0; g < 64; g++) s += partq[(long)g * 2048 + j];
    qbar[j] = (float)s;
}

__global__ __launch_bounds__(256) void u_kernel(const float* __restrict__ Wk,
                                                const float* __restrict__ qbar,
                                                float* __restrict__ U) {
    const int i = blockIdx.x, t = threadIdx.x;
#pragma unroll
    for (int r = 0; r < 2; r++) {
        const int e = r * 1024 + t * 4;
        float4 w = *(const float4*)(Wk + (long)i * 2048 + e);
        float4 q = *(const float4*)(qbar + e);
        float a = w.x * q.x + w.y * q.y + w.z * q.z + w.w * q.w;
#pragma unroll
        for (int off = 16; off; off >>= 1) a += __shfl_xor(a, off);
        if ((t & 31) == 0) U[(long)i * 16 + r * 8 + (t >> 5)] = a;
    }
}

// fused: HSb = bf16(hs row)  AND  imp[h,m] = hs[m,:] . U[:,h]
__global__ __launch_bounds__(256) void cast_imp_kernel(const float* __restrict__ hs,
                                                       const float* __restrict__ U,
                                                       unsigned short* __restrict__ HSb,
                                                       float* __restrict__ imp) {
    __shared__ float row[2048];
    __shared__ float red[4][16];
    const int m = blockIdx.x, t = threadIdx.x;
    for (int i = t; i < 2048; i += 256) {
        float v = hs[(long)m * 2048 + i];
        row[i] = v;
        HSb[(long)m * 2048 + i] = f2bf(v);
    }
    __syncthreads();
    float p[16];
#pragma unroll
    for (int h = 0; h < 16; h++) p[h] = 0.f;
    for (int i = t * 8; i < t * 8 + 8; i++) {
        const float v = row[i];
        const float* u = U + i * 16;
#pragma unroll
        for (int h = 0; h < 16; h++) p[h] += v * u[h];
    }
#pragma unroll
    for (int off = 32; off; off >>= 1)
#pragma unroll
        for (int h = 0; h < 16; h++) p[h] += __shfl_down(p[h], off);
    if ((t & 63) == 0)
#pragma unroll
        for (int h = 0; h < 16; h++) red[t >> 6][h] = p[h];
    __syncthreads();
    if (t < 16)
        imp[(long)t * 2048 + m] = red[0][t] + red[1][t] + red[2][t] + red[3][t];
}

// exact top-256 per head: one wave per head, register-resident, ballot counting
__global__ __launch_bounds__(64) void topk_kernel(const float* __restrict__ imp,
                                                  int* __restrict__ idx) {
    const int h = blockIdx.x;
    const int lane = threadIdx.x;
    unsigned u[32];
#pragma unroll
    for (int r = 0; r < 32; r++) {
        unsigned x = __float_as_uint(imp[(long)h * 2048 + r * 64 + lane]);
        u[r] = (x & 0x80000000u) ? ~x : (x | 0x80000000u);
    }
    unsigned cur = 0;
    for (int b = 31; b >= 0; b--) {
        const unsigned cand = cur | (1u << b);
        int tot = 0;
#pragma unroll
        for (int r = 0; r < 32; r++)
            tot += (int)__popcll(__ballot(u[r] >= cand));
        if (tot >= 256) cur = cand;
    }
    const unsigned long long below = (1ull << lane) - 1ull;
    int base = 0;
#pragma unroll
    for (int r = 0; r < 32; r++) {
        const bool q = u[r] > cur;
        const unsigned long long m = __ballot(q);
        if (q) idx[h * 256 + base + (int)__popcll(m & below)] = r * 64 + lane;
        base += (int)__popcll(m);
    }
#pragma unroll
    for (int r = 0; r < 32; r++) {
        const bool q = (u[r] == cur);
        const unsigned long long m = __ballot(q);
        if (q) {
            const int pos = base + (int)__popcll(m & below);
            if (pos < 256) idx[h * 256 + pos] = r * 64 + lane;
        }
        base += (int)__popcll(m);
        if (base >= 256) break;
    }
}

// Ksel[h][j][d] = K[idx[h][j]][h*128+d] ; VselT[h][d][j] = V[idx[h][j]][h*128+d]
__global__ void gather_kernel(const unsigned short* __restrict__ Kb,
                              const unsigned short* __restrict__ Vb,
                              const int* __restrict__ idx,
                              unsigned short* __restrict__ Ksel,
                              unsigned short* __restrict__ VselT) {
    int t = blockIdx.x * blockDim.x + threadIdx.x;   // 0..524287
    {
        int d = t & 127, j = (t >> 7) & 255, h = t >> 15;
        int sr = idx[h * 256 + j];
        Ksel[t] = Kb[(long)sr * 2048 + h * 128 + d];
    }
    {
        int j = t & 255, d = (t >> 8) & 127, h = t >> 15;
        int sr = idx[h * 256 + j];
        VselT[t] = Vb[(long)sr * 2048 + h * 128 + d];
    }
}

// ---------------------------------------------------------------------------
extern "C" void kernel_launch(void* const* d_in, const int* in_sizes, int n_in,
                              void* d_out, int out_size, void* d_ws, size_t ws_size,
                              hipStream_t stream)
{
    const float* hs = (const float*)d_in[0];
    const float* Wq = (const float*)d_in[1];
    const float* bq = (const float*)d_in[2];
    const float* Wk = (const float*)d_in[3];
    const float* bk = (const float*)d_in[4];
    const float* Wv = (const float*)d_in[5];
    const float* bv = (const float*)d_in[6];
    const float* Wo = (const float*)d_in[7];
    const float* bo = (const float*)d_in[8];

    char* ws = (char*)d_ws;
    size_t off = 0;
    auto alloc = [&](size_t b) -> void* {
        void* p = ws + off;
        off = (off + b + 255) & ~(size_t)255;
        return p;
    };
    unsigned short* HSb   = (unsigned short*)alloc(8388608);     // 2048x2048 bf16
    unsigned short* WT4   = (unsigned short*)alloc(4 * 8388608); // WqT|WkT|WvT|WoT
    unsigned short* QKVb  = (unsigned short*)alloc(3 * 8388608); // Q|K|V [3][2048][2048]
    unsigned short* Att   = (unsigned short*)alloc(8388608);
    unsigned short* Ksel  = (unsigned short*)alloc(1048576);     // [16][256][128]
    unsigned short* VselT = (unsigned short*)alloc(1048576);     // [16][128][256]
    double* part  = (double*)alloc(1048576);                     // [64][2048]
    float* hsbar = (float*)alloc(8192);
    float* qbar  = (float*)alloc(8192);
    float* U     = (float*)alloc(131072);                        // [2048][16]
    float* imp   = (float*)alloc(131072);                        // [16][2048]
    int*   idx   = (int*)alloc(16384);                           // [16][256]

    if (off > ws_size) {
        fill_kernel<<<4096, 256, 0, stream>>>((float*)d_out, 12345.0f, (long)out_size);
        return;
    }

    unsigned short* Qb = QKVb;
    unsigned short* Kb = QKVb + 4194304;
    unsigned short* Vb = QKVb + 2 * 4194304;
    unsigned short* WoT = WT4 + 3 * 4194304;

    // --- weight transposes (batched) ---
    transpose_cast4<<<dim3(64, 64, 4), dim3(32, 8), 0, stream>>>(Ptr4{{Wq, Wk, Wv, Wo}}, WT4);

    // --- ranking path (exact, deterministic) ---
    colsum_part<<<dim3(8, 64), 256, 0, stream>>>(hs, part);
    colsum_fin<<<32, 64, 0, stream>>>(part, hsbar);
    qsum_part<<<dim3(8, 64), 256, 0, stream>>>(hsbar, Wq, part);
    qsum_fin<<<32, 64, 0, stream>>>(part, bq, qbar);
    u_kernel<<<2048, 256, 0, stream>>>(Wk, qbar, U);
    cast_imp_kernel<<<2048, 256, 0, stream>>>(hs, U, HSb, imp);
    topk_kernel<<<16, 64, 0, stream>>>(imp, idx);

    // --- QKV batched GEMM: bf16 out + per-batch bias ---
    gemm_bf16<128, true><<<dim3(16, 16, 3), 256, 0, stream>>>(
        HSb, 2048, 0, WT4, 2048, 4194304, QKVb, 2048, 4194304,
        Bias3{bq, bk, bv}, 2048, 1.0f);

    // --- gather selected K/V ---
    gather_kernel<<<2048, 256, 0, stream>>>(Kb, Vb, idx, Ksel, VselT);

    // --- fused attention: S, softmax, PV ---
    attn_kernel<<<dim3(16, 16), 256, 0, stream>>>(Qb, Ksel, VselT, Att);

    // --- out = Att @ Wo + bo (fp32), 128x64 tiles for 2 blocks/CU ---
    gemm_bf16<64, false><<<dim3(32, 16, 1), 256, 0, stream>>>(
        Att, 2048, 0, WoT, 2048, 0, d_out, 2048, 0,
        Bias3{bo, bo, bo}, 2048, 1.0f);
}

// Round 4
// 335.042 us; speedup vs baseline: 2.0256x; 1.0092x over previous
//
#include <hip/hip_runtime.h>

// ---------------------------------------------------------------------------
// SparseAttention on MI355X (gfx950)
// hidden=2048, heads=16, d=128, topk=256, N=2048, B=1
//
// Ranking path (fp32/fp64, exact):  imp[h,m] = hs[m,:] . U[:,h]
//   where U[i,h] = sum_{j in head h} Wk[i,j]*qbar[j],  qbar = mean_n(HS) @ Wq + bq
// Value path (bf16 MFMA): QKV GEMM, fused topk+gather, fused attention, O GEMM.
// ---------------------------------------------------------------------------

typedef __attribute__((ext_vector_type(8))) short bf16x8;
typedef __attribute__((ext_vector_type(4))) float f32x4;

__device__ __forceinline__ unsigned short f2bf(float x) {
    unsigned u = __float_as_uint(x);
    u += 0x7fffu + ((u >> 16) & 1u);      // round to nearest even
    return (unsigned short)(u >> 16);
}

__device__ __forceinline__ void load_lds16(const unsigned short* g, unsigned short* l) {
    __builtin_amdgcn_global_load_lds(
        (const __attribute__((address_space(1))) unsigned int*)g,
        (__attribute__((address_space(3))) unsigned int*)l,
        16, 0, 0);
}

struct Bias3 { const float* p0; const float* p1; const float* p2; };
struct Ptr4  { const float* p[4]; };

// ---------------------------------------------------------------------------
// bf16 MFMA GEMM:  C[b,m,n] = alpha * sum_k A[b,m,k]*Bt[b,n,k] (+ bias_b[n])
// Tile 128 x TN (TN = 128 or 64), BK=32, 256 threads (2x2 waves).
// ---------------------------------------------------------------------------
template <int TN, bool OUT_BF16>
__global__ __launch_bounds__(256) void gemm_bf16(
    const unsigned short* __restrict__ A, long lda, long strideA,
    const unsigned short* __restrict__ Bt, long ldb, long strideB,
    void* __restrict__ Cv, long ldc, long strideC,
    Bias3 bias, int K, float alpha)
{
    constexpr int SN = TN / 32;                       // 16-col tiles per wave
    __shared__ __align__(16) unsigned short As[128][32];
    __shared__ __align__(16) unsigned short Bs[TN][32];

    const int tid  = threadIdx.x;
    const int lane = tid & 63;
    const int wave = tid >> 6;
    const int wm = wave >> 1, wn = wave & 1;

    const int bm = blockIdx.y * 128;
    const int bn = blockIdx.x * TN;
    const int b  = blockIdx.z;

    const unsigned short* Ab = A  + (long)b * strideA;
    const unsigned short* Bb = Bt + (long)b * strideB;

    f32x4 acc[4][SN];
#pragma unroll
    for (int i = 0; i < 4; i++)
#pragma unroll
        for (int j = 0; j < SN; j++) acc[i][j] = f32x4{0.f, 0.f, 0.f, 0.f};

    const int lr = lane >> 2;          // 0..15 row within 16-row staging group
    const int lc = (lane & 3) * 8;     // bf16 col offset (16B chunk)

    for (int k0 = 0; k0 < K; k0 += 32) {
        __syncthreads();
#pragma unroll
        for (int r0 = wave * 16; r0 < 128; r0 += 64)
            load_lds16(Ab + (long)(bm + r0 + lr) * lda + k0 + lc, &As[r0][0]);
#pragma unroll
        for (int r0 = wave * 16; r0 < TN; r0 += 64)
            load_lds16(Bb + (long)(bn + r0 + lr) * ldb + k0 + lc, &Bs[r0][0]);
        __syncthreads();

        bf16x8 af[4], bf[SN];
#pragma unroll
        for (int s = 0; s < 4; s++)
            af[s] = *(const bf16x8*)&As[wm * 64 + s * 16 + (lane & 15)][(lane >> 4) * 8];
#pragma unroll
        for (int t = 0; t < SN; t++)
            bf[t] = *(const bf16x8*)&Bs[wn * (TN / 2) + t * 16 + (lane & 15)][(lane >> 4) * 8];
#pragma unroll
        for (int s = 0; s < 4; s++)
#pragma unroll
            for (int t = 0; t < SN; t++)
                acc[s][t] = __builtin_amdgcn_mfma_f32_16x16x32_bf16(af[s], bf[t], acc[s][t], 0, 0, 0);
    }

    // epilogue: C/D layout col=lane&15, row=(lane>>4)*4+reg
    const float* bp = (b == 0) ? bias.p0 : (b == 1) ? bias.p1 : bias.p2;
    float* Cf = (float*)Cv;
    unsigned short* Ch = (unsigned short*)Cv;
#pragma unroll
    for (int s = 0; s < 4; s++) {
#pragma unroll
        for (int t = 0; t < SN; t++) {
            const int col  = bn + wn * (TN / 2) + t * 16 + (lane & 15);
            const int row0 = bm + wm * 64 + s * 16 + (lane >> 4) * 4;
            const float bv = bp ? bp[col] : 0.f;
#pragma unroll
            for (int r = 0; r < 4; r++) {
                float v = alpha * acc[s][t][r] + bv;
                long off = (long)b * strideC + (long)(row0 + r) * ldc + col;
                if (OUT_BF16) Ch[off] = f2bf(v);
                else          Cf[off] = v;
            }
        }
    }
}

// ---------------------------------------------------------------------------
// Fused attention, 64-query tiles (2 blocks/CU): S = scale*Q Ksel^T (fp32 regs),
// in-wave softmax, P(bf16)->LDS, O = P Vsel * (1/l), write to Att.
// ---------------------------------------------------------------------------
__global__ __launch_bounds__(256, 2) void attn_kernel(
    const unsigned short* __restrict__ Qb,     // [2048][2048] (token, h*128+d)
    const unsigned short* __restrict__ Ksel,   // [16][256][128]
    const unsigned short* __restrict__ VselT,  // [16][128][256]
    unsigned short* __restrict__ Att)          // [2048][2048]
{
    __shared__ __align__(16) unsigned short Qs[64][32];     //  4 KB
    __shared__ __align__(16) unsigned short Ks[256][32];    // 16 KB
    __shared__ __align__(16) unsigned short Vs[128][32];    //  8 KB
    __shared__ __align__(16) unsigned short Ps[64][264];    // 33 KB (pad 8)
    __shared__ float linv[64];

    const int tid  = threadIdx.x;
    const int lane = tid & 63;
    const int wave = tid >> 6;
    const int bm = blockIdx.x * 64;
    const int h  = blockIdx.y;
    const int lr = lane >> 2, lc = (lane & 3) * 8;

    const unsigned short* Kh = Ksel  + h * 32768;
    const unsigned short* Vh = VselT + h * 32768;

    // ---- phase 1: S tile 64x256, wave owns rows [wave*16, +16)
    f32x4 acc[16];
#pragma unroll
    for (int t = 0; t < 16; t++) acc[t] = f32x4{0.f, 0.f, 0.f, 0.f};

    for (int k0 = 0; k0 < 128; k0 += 32) {
        __syncthreads();
        load_lds16(Qb + (long)(bm + wave * 16 + lr) * 2048 + h * 128 + k0 + lc,
                   &Qs[wave * 16][0]);
#pragma unroll
        for (int q = 0; q < 4; q++)
            load_lds16(Kh + (wave * 64 + q * 16 + lr) * 128 + k0 + lc,
                       &Ks[wave * 64 + q * 16][0]);
        __syncthreads();

        bf16x8 af = *(const bf16x8*)&Qs[wave * 16 + (lane & 15)][(lane >> 4) * 8];
#pragma unroll
        for (int t = 0; t < 16; t++) {
            bf16x8 bfv = *(const bf16x8*)&Ks[t * 16 + (lane & 15)][(lane >> 4) * 8];
            acc[t] = __builtin_amdgcn_mfma_f32_16x16x32_bf16(af, bfv, acc[t], 0, 0, 0);
        }
    }

    // ---- phase 2: in-wave softmax over 256 cols; P = exp(scale*(s-max)), bf16
    const float se = 0.08838834764831845f * 1.4426950408889634f;  // scale*log2(e)
#pragma unroll
    for (int r = 0; r < 4; r++) {
        float mx = -3.0e38f;
#pragma unroll
        for (int t = 0; t < 16; t++) mx = fmaxf(mx, acc[t][r]);
#pragma unroll
        for (int off = 1; off < 16; off <<= 1) mx = fmaxf(mx, __shfl_xor(mx, off));
        float sum = 0.f;
#pragma unroll
        for (int t = 0; t < 16; t++) {
            float p = exp2f((acc[t][r] - mx) * se);
            acc[t][r] = p;
            sum += p;
        }
#pragma unroll
        for (int off = 1; off < 16; off <<= 1) sum += __shfl_xor(sum, off);
        const int row = wave * 16 + (lane >> 4) * 4 + r;
#pragma unroll
        for (int t = 0; t < 16; t++)
            Ps[row][t * 16 + (lane & 15)] = f2bf(acc[t][r]);
        if ((lane & 15) == 0) linv[row] = 1.0f / sum;
    }

    // ---- phase 3: O = P @ Vsel, 2x2 waves over 64x128
    const int wm2 = wave >> 1, wn2 = wave & 1;
    f32x4 acc2[2][4];
#pragma unroll
    for (int i = 0; i < 2; i++)
#pragma unroll
        for (int j = 0; j < 4; j++) acc2[i][j] = f32x4{0.f, 0.f, 0.f, 0.f};

    for (int j0 = 0; j0 < 256; j0 += 32) {
        __syncthreads();   // (also makes Ps/linv visible on first iteration)
#pragma unroll
        for (int q = 0; q < 2; q++)
            load_lds16(Vh + (wave * 32 + q * 16 + lr) * 256 + j0 + lc,
                       &Vs[wave * 32 + q * 16][0]);
        __syncthreads();

        bf16x8 af2[2], bf2v[4];
#pragma unroll
        for (int s2 = 0; s2 < 2; s2++)
            af2[s2] = *(const bf16x8*)&Ps[wm2 * 32 + s2 * 16 + (lane & 15)][j0 + (lane >> 4) * 8];
#pragma unroll
        for (int t2 = 0; t2 < 4; t2++)
            bf2v[t2] = *(const bf16x8*)&Vs[wn2 * 64 + t2 * 16 + (lane & 15)][(lane >> 4) * 8];
#pragma unroll
        for (int s2 = 0; s2 < 2; s2++)
#pragma unroll
            for (int t2 = 0; t2 < 4; t2++)
                acc2[s2][t2] = __builtin_amdgcn_mfma_f32_16x16x32_bf16(af2[s2], bf2v[t2], acc2[s2][t2], 0, 0, 0);
    }

    // ---- epilogue: divide by row sum, write Att[token][h*128+d]
#pragma unroll
    for (int s2 = 0; s2 < 2; s2++) {
#pragma unroll
        for (int t2 = 0; t2 < 4; t2++) {
            const int d = wn2 * 64 + t2 * 16 + (lane & 15);
#pragma unroll
            for (int r = 0; r < 4; r++) {
                const int row = wm2 * 32 + s2 * 16 + (lane >> 4) * 4 + r;
                float v = acc2[s2][t2][r] * linv[row];
                Att[(long)(bm + row) * 2048 + h * 128 + d] = f2bf(v);
            }
        }
    }
}

// ---------------------------------------------------------------------------
// prep: blocks [0,16384): fp32->bf16 transposed weights (4 matrices);
//       blocks [16384,16896): colsum partials of hs (ranking stage 1)
// ---------------------------------------------------------------------------
__global__ __launch_bounds__(256) void prep_kernel(Ptr4 srcs, unsigned short* __restrict__ WT4,
                                                   const float* __restrict__ hs,
                                                   double* __restrict__ part) {
    const int b = blockIdx.x;
    const int tid = threadIdx.x;
    if (b < 16384) {
        __shared__ float tile[32][33];
        const int z = b >> 12, xy = b & 4095;
        const float* W = srcs.p[z];
        unsigned short* WT = WT4 + (long)z * 4194304;
        const int bx = (xy & 63) * 32;   // n
        const int by = (xy >> 6) * 32;   // k
        const int x = tid & 31, y = tid >> 5;   // y in 0..7
#pragma unroll
        for (int i = 0; i < 32; i += 8)
            tile[y + i][x] = W[(long)(by + y + i) * 2048 + bx + x];
        __syncthreads();
#pragma unroll
        for (int i = 0; i < 32; i += 8)
            WT[(long)(bx + y + i) * 2048 + by + x] = f2bf(tile[x][y + i]);
    } else {
        const int c = b - 16384;                 // 0..511
        const int col = (c & 7) * 256 + tid;
        const int r0  = (c >> 3) * 32;
        double a = 0.0;
#pragma unroll 4
        for (int r = 0; r < 32; r++) a += (double)hs[(long)(r0 + r) * 2048 + col];
        part[(long)(c >> 3) * 2048 + col] = a;
    }
}

__global__ void fill_kernel(float* p, float v, long n) {
    long i = ((long)blockIdx.x * blockDim.x + threadIdx.x) * 4;
    if (i + 3 < n) { p[i] = v; p[i+1] = v; p[i+2] = v; p[i+3] = v; }
}

// ---------------------------------------------------------------------------
// Ranking path
// ---------------------------------------------------------------------------
// fused colsum finish + qsum partial: each block re-derives its 32 hsbar values
// (bit-identical order: g ascending), then partial qbar sums.
__global__ __launch_bounds__(256) void mean_qsum_part(const double* __restrict__ part,
                                                      const float* __restrict__ Wq,
                                                      double* __restrict__ partq) {
    __shared__ float hsb[32];
    const int j  = blockIdx.x * 256 + threadIdx.x;
    const int i0 = blockIdx.y * 32;
    if (threadIdx.x < 32) {
        double s = 0.0;
#pragma unroll 4
        for (int g = 0; g < 64; g++) s += part[(long)g * 2048 + i0 + threadIdx.x];
        hsb[threadIdx.x] = (float)(s * (1.0 / 2048.0));
    }
    __syncthreads();
    double a = 0.0;
#pragma unroll 4
    for (int r = 0; r < 32; r++)
        a += (double)hsb[r] * (double)Wq[(long)(i0 + r) * 2048 + j];
    partq[(long)blockIdx.y * 2048 + j] = a;
}

__global__ void qsum_fin(const double* __restrict__ partq, const float* __restrict__ bq,
                         float* __restrict__ qbar) {
    const int j = blockIdx.x * 64 + threadIdx.x;
    double s = (double)bq[j];
#pragma unroll 4
    for (int g = 0; g < 64; g++) s += partq[(long)g * 2048 + j];
    qbar[j] = (float)s;
}

__global__ __launch_bounds__(256) void u_kernel(const float* __restrict__ Wk,
                                                const float* __restrict__ qbar,
                                                float* __restrict__ U) {
    const int i = blockIdx.x, t = threadIdx.x;
#pragma unroll
    for (int r = 0; r < 2; r++) {
        const int e = r * 1024 + t * 4;
        float4 w = *(const float4*)(Wk + (long)i * 2048 + e);
        float4 q = *(const float4*)(qbar + e);
        float a = w.x * q.x + w.y * q.y + w.z * q.z + w.w * q.w;
#pragma unroll
        for (int off = 16; off; off >>= 1) a += __shfl_xor(a, off);
        if ((t & 31) == 0) U[(long)i * 16 + r * 8 + (t >> 5)] = a;
    }
}

// fused: HSb = bf16(hs row)  AND  imp[h,m] = hs[m,:] . U[:,h]
__global__ __launch_bounds__(256) void cast_imp_kernel(const float* __restrict__ hs,
                                                       const float* __restrict__ U,
                                                       unsigned short* __restrict__ HSb,
                                                       float* __restrict__ imp) {
    __shared__ float row[2048];
    __shared__ float red[4][16];
    const int m = blockIdx.x, t = threadIdx.x;
    for (int i = t; i < 2048; i += 256) {
        float v = hs[(long)m * 2048 + i];
        row[i] = v;
        HSb[(long)m * 2048 + i] = f2bf(v);
    }
    __syncthreads();
    float p[16];
#pragma unroll
    for (int h = 0; h < 16; h++) p[h] = 0.f;
    for (int i = t * 8; i < t * 8 + 8; i++) {
        const float v = row[i];
        const float* u = U + i * 16;
#pragma unroll
        for (int h = 0; h < 16; h++) p[h] += v * u[h];
    }
#pragma unroll
    for (int off = 32; off; off >>= 1)
#pragma unroll
        for (int h = 0; h < 16; h++) p[h] += __shfl_down(p[h], off);
    if ((t & 63) == 0)
#pragma unroll
        for (int h = 0; h < 16; h++) red[t >> 6][h] = p[h];
    __syncthreads();
    if (t < 16)
        imp[(long)t * 2048 + m] = red[0][t] + red[1][t] + red[2][t] + red[3][t];
}

// ---------------------------------------------------------------------------
// fused topk + gather: one block per head. Wave 0: exact top-256 (register-
// resident ballot binary search, ties lowest-index-first) into LDS; then all
// 4 waves gather Ksel[h][j][d] and VselT[h][d][j] (transpose via LDS tile).
// ---------------------------------------------------------------------------
__global__ __launch_bounds__(256) void topk_gather(const float* __restrict__ imp,
                                                   const unsigned short* __restrict__ Kb,
                                                   const unsigned short* __restrict__ Vb,
                                                   unsigned short* __restrict__ Ksel,
                                                   unsigned short* __restrict__ VselT) {
    __shared__ int sidx[256];
    __shared__ unsigned short Vt[64][130];   // 64 j x 128 d, pad 2
    const int h = blockIdx.x;
    const int tid = threadIdx.x;
    const int lane = tid & 63;
    const int wave = tid >> 6;

    if (wave == 0) {
        unsigned u[32];
#pragma unroll
        for (int r = 0; r < 32; r++) {
            unsigned x = __float_as_uint(imp[(long)h * 2048 + r * 64 + lane]);
            u[r] = (x & 0x80000000u) ? ~x : (x | 0x80000000u);
        }
        unsigned cur = 0;
        for (int b = 31; b >= 0; b--) {
            const unsigned cand = cur | (1u << b);
            int tot = 0;
#pragma unroll
            for (int r = 0; r < 32; r++)
                tot += (int)__popcll(__ballot(u[r] >= cand));
            if (tot >= 256) cur = cand;
        }
        const unsigned long long below = (1ull << lane) - 1ull;
        int base = 0;
#pragma unroll
        for (int r = 0; r < 32; r++) {
            const bool q = u[r] > cur;
            const unsigned long long m = __ballot(q);
            if (q) sidx[base + (int)__popcll(m & below)] = r * 64 + lane;
            base += (int)__popcll(m);
        }
#pragma unroll
        for (int r = 0; r < 32; r++) {
            const bool q = (u[r] == cur);
            const unsigned long long m = __ballot(q);
            if (q) {
                const int pos = base + (int)__popcll(m & below);
                if (pos < 256) sidx[pos] = r * 64 + lane;
            }
            base += (int)__popcll(m);
            if (base >= 256) break;
        }
    }
    __syncthreads();

    // K gather: wave w handles j = w*64 .. w*64+63; coalesced 4B per lane
    unsigned short* Kh = Ksel + h * 32768;
#pragma unroll 4
    for (int jj = 0; jj < 64; jj++) {
        const int j = wave * 64 + jj;
        const long sr = sidx[j];
        *(ushort2*)&Kh[j * 128 + lane * 2] =
            *(const ushort2*)&Kb[sr * 2048 + h * 128 + lane * 2];
    }

    // V gather + transpose via LDS, 4 chunks of 64 j
    unsigned short* Vh = VselT + h * 32768;
    for (int j0 = 0; j0 < 256; j0 += 64) {
        __syncthreads();
#pragma unroll 4
        for (int jj = 0; jj < 16; jj++) {
            const int jl = wave * 16 + jj;          // 0..63 within chunk
            const long sr = sidx[j0 + jl];
            *(ushort2*)&Vt[jl][lane * 2] =
                *(const ushort2*)&Vb[sr * 2048 + h * 128 + lane * 2];
        }
        __syncthreads();
#pragma unroll 8
        for (int d = wave; d < 128; d += 4) {
            Vh[d * 256 + j0 + lane] = Vt[lane][d];
        }
    }
}

// ---------------------------------------------------------------------------
extern "C" void kernel_launch(void* const* d_in, const int* in_sizes, int n_in,
                              void* d_out, int out_size, void* d_ws, size_t ws_size,
                              hipStream_t stream)
{
    const float* hs = (const float*)d_in[0];
    const float* Wq = (const float*)d_in[1];
    const float* bq = (const float*)d_in[2];
    const float* Wk = (const float*)d_in[3];
    const float* bk = (const float*)d_in[4];
    const float* Wv = (const float*)d_in[5];
    const float* bv = (const float*)d_in[6];
    const float* Wo = (const float*)d_in[7];
    const float* bo = (const float*)d_in[8];

    char* ws = (char*)d_ws;
    size_t off = 0;
    auto alloc = [&](size_t b) -> void* {
        void* p = ws + off;
        off = (off + b + 255) & ~(size_t)255;
        return p;
    };
    unsigned short* HSb   = (unsigned short*)alloc(8388608);     // 2048x2048 bf16
    unsigned short* WT4   = (unsigned short*)alloc(4 * 8388608); // WqT|WkT|WvT|WoT
    unsigned short* QKVb  = (unsigned short*)alloc(3 * 8388608); // Q|K|V [3][2048][2048]
    unsigned short* Att   = (unsigned short*)alloc(8388608);
    unsigned short* Ksel  = (unsigned short*)alloc(1048576);     // [16][256][128]
    unsigned short* VselT = (unsigned short*)alloc(1048576);     // [16][128][256]
    double* part  = (double*)alloc(1048576);                     // [64][2048]
    double* partq = (double*)alloc(1048576);                     // [64][2048]
    float* qbar  = (float*)alloc(8192);
    float* U     = (float*)alloc(131072);                        // [2048][16]
    float* imp   = (float*)alloc(131072);                        // [16][2048]

    if (off > ws_size) {
        fill_kernel<<<4096, 256, 0, stream>>>((float*)d_out, 12345.0f, (long)out_size);
        return;
    }

    unsigned short* Qb = QKVb;
    unsigned short* Kb = QKVb + 4194304;
    unsigned short* Vb = QKVb + 2 * 4194304;
    unsigned short* WoT = WT4 + 3 * 4194304;

    // 1. weight transposes + colsum partials (fused, independent roles)
    prep_kernel<<<16896, 256, 0, stream>>>(Ptr4{{Wq, Wk, Wv, Wo}}, WT4, hs, part);

    // 2-5. ranking chain (exact, deterministic)
    mean_qsum_part<<<dim3(8, 64), 256, 0, stream>>>(part, Wq, partq);
    qsum_fin<<<32, 64, 0, stream>>>(partq, bq, qbar);
    u_kernel<<<2048, 256, 0, stream>>>(Wk, qbar, U);
    cast_imp_kernel<<<2048, 256, 0, stream>>>(hs, U, HSb, imp);

    // 6. QKV batched GEMM: bf16 out + per-batch bias
    gemm_bf16<128, true><<<dim3(16, 16, 3), 256, 0, stream>>>(
        HSb, 2048, 0, WT4, 2048, 4194304, QKVb, 2048, 4194304,
        Bias3{bq, bk, bv}, 2048, 1.0f);

    // 7. top-256 per head + gather selected K/V (fused)
    topk_gather<<<16, 256, 0, stream>>>(imp, Kb, Vb, Ksel, VselT);

    // 8. fused attention: S, softmax, PV  (64-query tiles, 2 blocks/CU)
    attn_kernel<<<dim3(32, 16), 256, 0, stream>>>(Qb, Ksel, VselT, Att);

    // 9. out = Att @ Wo + bo (fp32), 128x64 tiles for 2 blocks/CU
    gemm_bf16<64, false><<<dim3(32, 16, 1), 256, 0, stream>>>(
        Att, 2048, 0, WoT, 2048, 0, d_out, 2048, 0,
        Bias3{bo, bo, bo}, 2048, 1.0f);
}